// Round 12
// baseline (113.792 us; speedup 1.0000x reference)
//
#include <hip/hip_runtime.h>
#include <hip/hip_bf16.h>

// Problem shapes
#define B_SZ 64
#define T_PTS 300
#define N_SEG 299        // number of segments
#define VM 34            // 17*2
#define NPATH (B_SZ*VM)  // 2176
#define SIGC 120         // 3+9+27+81
#define FAN1 4080        // 34*120
#define H1 512
#define NOUT 155
#define CHUNK 5          // segments per lane (64*5=320 >= 299, 7% waste)
#define KSPL 48          // gemm1 K-splits
#define KW 85            // k per wave (48*85 = 4080)
#define JPW 8            // gemm1 j-rows per wave
#define NXCD 8           // MI355X XCD count; NPATH = 8*272 exactly (bijective)

// ---------------------------------------------------------------------------
// SESSION JOURNAL (why this exact configuration):
//  R11 = best: 112.8 us (R6-config + XCD swizzle).
//  R6/R10 base config: 114.2 / 115.7 us (R3 113.96 w/ separate transpose).
//  R7  coop-LDS-tree combine: 115.5 (neutral) -> shfl butterflies kept.
//  R8  amdgpu_waves_per_eu(3): allocator SPILLED the 120-float state
//      (VGPR 136->84, 400 MB scratch HBM, sig 138 us). NEVER raise it.
//  R9  2-wave/path split: sig 44.5 us vs ~33 at 1-wave (+25% issues, +33%
//      loads, 3 barriers). State too big to split without spill/redundancy.
//      ALSO measured: 3x inp over-fetch without XCD swizzle -> R11 fix.
//  R4  v_permlane16/32_swap butterflies: WRONG DIRECTION (absmax 497).
//      Do not reintroduce without an isolated semantics probe.
//  R12 (this round): explicit 18-load register prefetch before the append
//      loop (VGPR is free: occupancy ladder steps at 128/170/256 and the
//      grid supplies only 2.1 waves/SIMD vs the 3-wave VGPR cap at 136).
// ---------------------------------------------------------------------------

// ---------------------------------------------------------------------------
// Absorb one linear segment with increment d into state a1..a4.
// Horner-factored (segment signature = exp(d)): 189 VALU ops vs ~480 naive.
// ---------------------------------------------------------------------------
__device__ __forceinline__ void sig_append(float a1[3], float a2[9], float a3[27], float a4[81],
                                           float d0, float d1, float d2) {
  const float d[3] = {d0, d1, d2};

  // Level 4 (uses OLD a1,a2,a3)
  float Z[3], Y[9], X[27];
#pragma unroll
  for (int i = 0; i < 3; i++) Z[i] = fmaf(d[i], 1.0f / 24.0f, (1.0f / 6.0f) * a1[i]);
#pragma unroll
  for (int e = 0; e < 9; e++) Y[e] = fmaf(d[e % 3], Z[e / 3], 0.5f * a2[e]);
#pragma unroll
  for (int e = 0; e < 27; e++) X[e] = fmaf(d[e % 3], Y[e / 3], a3[e]);
#pragma unroll
  for (int e = 0; e < 81; e++) a4[e] = fmaf(d[e % 3], X[e / 3], a4[e]);

  // Level 3 (uses OLD a1,a2)
  float Z3[3], Y3[9];
#pragma unroll
  for (int i = 0; i < 3; i++) Z3[i] = fmaf(d[i], 1.0f / 6.0f, 0.5f * a1[i]);
#pragma unroll
  for (int e = 0; e < 9; e++) Y3[e] = fmaf(d[e % 3], Z3[e / 3], a2[e]);
#pragma unroll
  for (int e = 0; e < 27; e++) a3[e] = fmaf(d[e % 3], Y3[e / 3], a3[e]);

  // Level 2 (uses OLD a1)
  float Z2[3];
#pragma unroll
  for (int i = 0; i < 3; i++) Z2[i] = fmaf(d[i], 0.5f, a1[i]);
#pragma unroll
  for (int e = 0; e < 9; e++) a2[e] = fmaf(d[e % 3], Z2[e / 3], a2[e]);

#pragma unroll
  for (int i = 0; i < 3; i++) a1[i] += d[i];
}

// ---------------------------------------------------------------------------
// Cross-lane fetch for the Chen combine.
//   OFF < 16 : DPP row_shl:OFF -> lane i reads lane i+OFF within its 16-lane
//              row; out-of-row lanes get 0 (= Chen identity). VALU pipe.
//   OFF >= 16: __shfl_xor butterfly (VERIFIED R2/R3/R5/R6/R10/R11). Only
//              lane 0's chain is consumed; its partners (lane 16 pre-round,
//              lane 32 post-round-16) are always valid suffix products.
// ---------------------------------------------------------------------------
template <int OFF>
__device__ __forceinline__ float lane_down(float x) {
  if constexpr (OFF < 16) {
    return __int_as_float(__builtin_amdgcn_update_dpp(
        0, __float_as_int(x), 0x100 + OFF /*row_shl:OFF*/, 0xF, 0xF, true));
  } else {
    return __shfl_xor(x, OFF);
  }
}

// One Chen-combine round: state <- state (x) fetched-state.
template <int OFF>
__device__ __forceinline__ void chen_round(float a1[3], float a2[9], float a3[27], float a4[81]) {
  float B1[3], B2[9], B3[27];
#pragma unroll
  for (int i = 0; i < 3; i++) B1[i] = lane_down<OFF>(a1[i]);
#pragma unroll
  for (int i = 0; i < 9; i++) B2[i] = lane_down<OFF>(a2[i]);
#pragma unroll
  for (int i = 0; i < 27; i++) B3[i] = lane_down<OFF>(a3[i]);

#pragma unroll
  for (int e = 0; e < 81; e++) {
    const float b4 = lane_down<OFF>(a4[e]);  // reads pre-update a4[e]
    float v = a4[e] + b4;
    v = fmaf(a3[e / 3], B1[e % 3], v);
    v = fmaf(a2[e / 9], B2[e % 9], v);
    v = fmaf(a1[e / 27], B3[e % 27], v);
    a4[e] = v;
  }
#pragma unroll
  for (int e = 0; e < 27; e++) {
    float v = a3[e] + B3[e];
    v = fmaf(a2[e / 3], B1[e % 3], v);
    v = fmaf(a1[e / 9], B2[e % 9], v);
    a3[e] = v;
  }
#pragma unroll
  for (int e = 0; e < 9; e++) a2[e] = fmaf(a1[e / 3], B1[e % 3], a2[e] + B2[e]);
#pragma unroll
  for (int i = 0; i < 3; i++) a1[i] += B1[i];
}

// ---------------------------------------------------------------------------
// Kernel 1: signatures, reading inp directly (no transpose stage).
// inp layout: (B, C, T, V*M) -> element ((b*3+c)*300 + t)*34 + vm.
// XCD SWIZZLE (R11): p = (bid&7)*272 + (bid>>3). All 34 same-b blocks run
// on one XCD -> the 122 KB b-slice is fetched into that L2 once, reused 33x.
// REGISTER PREFETCH (R12): all 18 strided loads are issued back-to-back
// into pts[6][3] BEFORE any arithmetic -> one pipelined latency window
// instead of 5 exposed per-iteration windows (only ~2.1 waves/SIMD exist
// to hide them). VGPR cost ~+15 is free (grid-limited below the VGPR cap).
// One PATH per WAVE (2176 one-wave blocks). 64 lanes x 5 Horner appends,
// then Chen combine: 4 DPP row rounds + 2 shfl_xor butterfly rounds.
// t-indices clamped to 299; invalid segments get d=0 (identity).
// 512 of the blocks zero one ht row each (b1 folded into gemm2).
// Output TRANSPOSED: St[k][b], k = vm*120 + c.
// ---------------------------------------------------------------------------
__global__ __launch_bounds__(64)
__attribute__((amdgpu_waves_per_eu(1)))
void sig_kernel(const float* __restrict__ inp, float* __restrict__ St,
                float* __restrict__ ht) {
  const int lane = threadIdx.x & 63;
  const int bid = blockIdx.x;       // 0..2175
  const int p = (bid & (NXCD - 1)) * (NPATH / NXCD) + (bid >> 3);  // bijective
  if (p < H1) ht[(size_t)p * 64 + lane] = 0.0f;  // zero-init for gemm1 atomics

  const int b = p / VM;
  const int vm = p - b * VM;
  const int t0 = lane * CHUNK;

  // base points at (b, c=0, t=0, vm); channel stride = T_PTS*VM = 10200,
  // t stride = VM = 34 (floats).
  const float* base = inp + (size_t)b * 3 * T_PTS * VM + vm;

  // ---- R12: issue ALL 18 loads first (static indices -> registers) ----
  float pts[CHUNK + 1][3];
#pragma unroll
  for (int s = 0; s <= CHUNK; s++) {
    const int t = t0 + s;
    const int tc = t < N_SEG ? t : N_SEG;   // clamp (in-bounds, d masked later)
#pragma unroll
    for (int c = 0; c < 3; c++) pts[s][c] = base[c * T_PTS * VM + tc * VM];
  }

  float a1[3], a2[9], a3[27], a4[81];
#pragma unroll
  for (int i = 0; i < 3; i++) a1[i] = 0.f;
#pragma unroll
  for (int i = 0; i < 9; i++) a2[i] = 0.f;
#pragma unroll
  for (int i = 0; i < 27; i++) a3[i] = 0.f;
#pragma unroll
  for (int i = 0; i < 81; i++) a4[i] = 0.f;

#pragma unroll
  for (int s = 0; s < CHUNK; s++) {
    const bool valid = (t0 + s) < N_SEG;
    const float d0 = valid ? (pts[s + 1][0] - pts[s][0]) : 0.0f;
    const float d1 = valid ? (pts[s + 1][1] - pts[s][1]) : 0.0f;
    const float d2 = valid ? (pts[s + 1][2] - pts[s][2]) : 0.0f;
    sig_append(a1, a2, a3, a4, d0, d1, d2);
  }

  // Row-local suffix Chen product (16-lane Kogge-Stone via DPP).
  chen_round<1>(a1, a2, a3, a4);
  chen_round<2>(a1, a2, a3, a4);
  chen_round<4>(a1, a2, a3, a4);
  chen_round<8>(a1, a2, a3, a4);
  // Cross-row butterfly: lane 0 <- S(0..31) <- S(0..63).
  chen_round<16>(a1, a2, a3, a4);
  chen_round<32>(a1, a2, a3, a4);

  if (lane == 0) {
    float* dst = St + (size_t)(vm * SIGC) * 64 + b;  // St[(vm*120+i)*64 + b]
#pragma unroll
    for (int i = 0; i < 3; i++) dst[(size_t)i * 64] = a1[i];
#pragma unroll
    for (int i = 0; i < 9; i++) dst[(size_t)(3 + i) * 64] = a2[i];
#pragma unroll
    for (int i = 0; i < 27; i++) dst[(size_t)(12 + i) * 64] = a3[i];
#pragma unroll
    for (int i = 0; i < 81; i++) dst[(size_t)(39 + i) * 64] = a4[i];
  }
}

// ---------------------------------------------------------------------------
// Kernel 2: ht[j][b] += sum_k St[k][b] * W1[j][k].  lane = b (M=64=wave).
// 3072 waves: 48 K-splits (85 k each) x 64 j-groups (8 j each). sv[85]
// register-resident (static indices); W1 rows are wave-uniform streams
// (scalar loads). 8 independent FMA chains. Coalesced atomicAdd epilogue
// onto the zero-initialized ht (48 adds/element, order-independent).
// ---------------------------------------------------------------------------
__global__ __launch_bounds__(256) void gemm1_kernel(const float* __restrict__ St,
                                                    const float* __restrict__ W1,
                                                    float* __restrict__ ht) {
  const int lane = threadIdx.x & 63;
  int wave_id = (blockIdx.x * 256 + threadIdx.x) >> 6;        // 0..3071
  wave_id = __builtin_amdgcn_readfirstlane(wave_id);          // force SGPR
  const int ks = wave_id >> 6;    // 0..47  (k-range of 85)
  const int jg = wave_id & 63;    // 0..63  (8 j's each)
  const int k0 = ks * KW;

  const float* stp = St + (size_t)k0 * 64 + lane;
  const float* w[JPW];
#pragma unroll
  for (int r = 0; r < JPW; r++) w[r] = W1 + (size_t)(jg * JPW + r) * FAN1 + k0;  // uniform -> s_load

  float sv[KW];
#pragma unroll
  for (int i = 0; i < KW; i++) sv[i] = stp[(size_t)i * 64];

  float acc[JPW];
#pragma unroll
  for (int r = 0; r < JPW; r++) acc[r] = 0.f;

#pragma unroll
  for (int i = 0; i < KW; i++) {
#pragma unroll
    for (int r = 0; r < JPW; r++) acc[r] = fmaf(sv[i], w[r][i], acc[r]);
  }

  float* hp = ht + (size_t)(jg * JPW) * 64 + lane;
#pragma unroll
  for (int r = 0; r < JPW; r++) atomicAdd(hp + r * 64, acc[r]);
}

// ---------------------------------------------------------------------------
// Kernel 3: out[b][j] = sum_k2 (ht[k2][b] + b1[k2]) * W2[j][k2] + b2[j].
// lane = b. Block = one j; 4 waves split k2 (128 each). The b1 fold is a
// second wave-uniform FMA chain in the same loop; red[w] = acc + accb so
// the LDS reduce also sums the b1·W2[j] correction. Single non-atomic store.
// ---------------------------------------------------------------------------
__global__ __launch_bounds__(256) void gemm2_kernel(const float* __restrict__ ht,
                                                    const float* __restrict__ W2,
                                                    const float* __restrict__ b1,
                                                    const float* __restrict__ b2,
                                                    float* __restrict__ out) {
  const int j = blockIdx.x;              // 0..154
  const int lane = threadIdx.x & 63;
  int w = threadIdx.x >> 6;              // 0..3
  w = __builtin_amdgcn_readfirstlane(w);
  __shared__ float red[4][64];

  const float* htp = ht + (size_t)(w * 128) * 64 + lane;
  const float* w2r = W2 + (size_t)j * H1 + w * 128;  // uniform -> s_load
  const float* b1r = b1 + w * 128;                   // uniform -> s_load
  float acc = 0.f, accb = 0.f;
#pragma unroll 8
  for (int k = 0; k < 128; k++) {
    const float wv = w2r[k];
    acc = fmaf(wv, htp[(size_t)k * 64], acc);
    accb = fmaf(wv, b1r[k], accb);
  }

  red[w][lane] = acc + accb;
  __syncthreads();
  if (threadIdx.x < 64) {
    const float tot = red[0][lane] + red[1][lane] + red[2][lane] + red[3][lane];
    out[(size_t)lane * NOUT + j] = tot + b2[j];
  }
}

// ---------------------------------------------------------------------------
extern "C" void kernel_launch(void* const* d_in, const int* in_sizes, int n_in,
                              void* d_out, int out_size, void* d_ws, size_t ws_size,
                              hipStream_t stream) {
  const float* inp = (const float*)d_in[0];  // (64,3,300,17,2)
  const float* W1  = (const float*)d_in[1];  // (512,4080)
  const float* b1  = (const float*)d_in[2];  // (512,)
  const float* W2  = (const float*)d_in[3];  // (155,512)
  const float* b2  = (const float*)d_in[4];  // (155,)
  float* out = (float*)d_out;                // (64,155)

  // ws layout (floats): St | ht   (~1.2 MB total)
  float* St = (float*)d_ws;                  // 4080*64
  float* ht = St + (size_t)FAN1 * 64;        // 512*64

  sig_kernel<<<NPATH, 64, 0, stream>>>(inp, St, ht);
  gemm1_kernel<<<KSPL * 64 / 4, 256, 0, stream>>>(St, W1, ht);
  gemm2_kernel<<<NOUT, 256, 0, stream>>>(ht, W2, b1, b2, out);
}

// Round 13
// 113.673 us; speedup vs baseline: 1.0011x; 1.0011x over previous
//
#include <hip/hip_runtime.h>
#include <hip/hip_bf16.h>

// Problem shapes
#define B_SZ 64
#define T_PTS 300
#define N_SEG 299        // number of segments
#define VM 34            // 17*2
#define NPATH (B_SZ*VM)  // 2176
#define SIGC 120         // 3+9+27+81
#define FAN1 4080        // 34*120
#define H1 512
#define NOUT 155
#define CHUNK 5          // segments per lane (64*5=320 >= 299, 7% waste)
#define KSPL 48          // gemm1 K-splits
#define KW 85            // k per wave (48*85 = 4080)
#define JPW 8            // gemm1 j-rows per wave
#define NXCD 8           // MI355X XCD count; NPATH = 8*272 exactly (bijective)

// ---------------------------------------------------------------------------
// SESSION JOURNAL (why this exact configuration — R11 = measured best):
//  R11 = best: 112.8 us (R6-config + XCD swizzle). THIS FILE = exact R11.
//  R6/R10 base config: 114.2 / 115.7 us (R3 113.96 w/ separate transpose).
//  R7  coop-LDS-tree combine: 115.5 (neutral) -> shfl butterflies kept.
//  R8  amdgpu_waves_per_eu(3): allocator SPILLED the 120-float state
//      (VGPR 136->84, 400 MB scratch HBM, sig 138 us). NEVER raise it.
//  R9  2-wave/path split: sig 44.5 us vs ~33 at 1-wave (+25% issues, +33%
//      loads, 3 barriers). State too big to split without spill/redundancy.
//  R12 18-load register prefetch: sig <42 -> 58-62 us in profile (VALUBusy
//      31->20%). Bursting uncoalesced 4B loads congests the VMEM path
//      (16x line amplification); the compiler's interleaved schedule was
//      already right. REVERTED. Do not hoist the strided loads.
//  R11 ALSO confirmed: sig FETCH 30.7 MB -> 4.0 MB with the XCD swizzle
//      (inp slice fetched once per XCD L2, reused 33x). Keep the swizzle.
//  R4  v_permlane16/32_swap butterflies: WRONG DIRECTION (absmax 497).
//      Do not reintroduce without an isolated semantics probe.
//  Status: all sig structural levers refuted; remaining profile = 42 us
//  harness poison-fill at 80% HBM peak (uncontrollable) + latency-bound sig
//  + ~10 us GEMM/launch floor. Session converged at ~113 us.
// ---------------------------------------------------------------------------

// ---------------------------------------------------------------------------
// Absorb one linear segment with increment d into state a1..a4.
// Horner-factored (segment signature = exp(d)): 189 VALU ops vs ~480 naive.
// ---------------------------------------------------------------------------
__device__ __forceinline__ void sig_append(float a1[3], float a2[9], float a3[27], float a4[81],
                                           float d0, float d1, float d2) {
  const float d[3] = {d0, d1, d2};

  // Level 4 (uses OLD a1,a2,a3)
  float Z[3], Y[9], X[27];
#pragma unroll
  for (int i = 0; i < 3; i++) Z[i] = fmaf(d[i], 1.0f / 24.0f, (1.0f / 6.0f) * a1[i]);
#pragma unroll
  for (int e = 0; e < 9; e++) Y[e] = fmaf(d[e % 3], Z[e / 3], 0.5f * a2[e]);
#pragma unroll
  for (int e = 0; e < 27; e++) X[e] = fmaf(d[e % 3], Y[e / 3], a3[e]);
#pragma unroll
  for (int e = 0; e < 81; e++) a4[e] = fmaf(d[e % 3], X[e / 3], a4[e]);

  // Level 3 (uses OLD a1,a2)
  float Z3[3], Y3[9];
#pragma unroll
  for (int i = 0; i < 3; i++) Z3[i] = fmaf(d[i], 1.0f / 6.0f, 0.5f * a1[i]);
#pragma unroll
  for (int e = 0; e < 9; e++) Y3[e] = fmaf(d[e % 3], Z3[e / 3], a2[e]);
#pragma unroll
  for (int e = 0; e < 27; e++) a3[e] = fmaf(d[e % 3], Y3[e / 3], a3[e]);

  // Level 2 (uses OLD a1)
  float Z2[3];
#pragma unroll
  for (int i = 0; i < 3; i++) Z2[i] = fmaf(d[i], 0.5f, a1[i]);
#pragma unroll
  for (int e = 0; e < 9; e++) a2[e] = fmaf(d[e % 3], Z2[e / 3], a2[e]);

#pragma unroll
  for (int i = 0; i < 3; i++) a1[i] += d[i];
}

// ---------------------------------------------------------------------------
// Cross-lane fetch for the Chen combine.
//   OFF < 16 : DPP row_shl:OFF -> lane i reads lane i+OFF within its 16-lane
//              row; out-of-row lanes get 0 (= Chen identity). VALU pipe.
//   OFF >= 16: __shfl_xor butterfly (VERIFIED R2/R3/R5/R6/R10/R11). Only
//              lane 0's chain is consumed; its partners (lane 16 pre-round,
//              lane 32 post-round-16) are always valid suffix products.
// ---------------------------------------------------------------------------
template <int OFF>
__device__ __forceinline__ float lane_down(float x) {
  if constexpr (OFF < 16) {
    return __int_as_float(__builtin_amdgcn_update_dpp(
        0, __float_as_int(x), 0x100 + OFF /*row_shl:OFF*/, 0xF, 0xF, true));
  } else {
    return __shfl_xor(x, OFF);
  }
}

// One Chen-combine round: state <- state (x) fetched-state.
template <int OFF>
__device__ __forceinline__ void chen_round(float a1[3], float a2[9], float a3[27], float a4[81]) {
  float B1[3], B2[9], B3[27];
#pragma unroll
  for (int i = 0; i < 3; i++) B1[i] = lane_down<OFF>(a1[i]);
#pragma unroll
  for (int i = 0; i < 9; i++) B2[i] = lane_down<OFF>(a2[i]);
#pragma unroll
  for (int i = 0; i < 27; i++) B3[i] = lane_down<OFF>(a3[i]);

#pragma unroll
  for (int e = 0; e < 81; e++) {
    const float b4 = lane_down<OFF>(a4[e]);  // reads pre-update a4[e]
    float v = a4[e] + b4;
    v = fmaf(a3[e / 3], B1[e % 3], v);
    v = fmaf(a2[e / 9], B2[e % 9], v);
    v = fmaf(a1[e / 27], B3[e % 27], v);
    a4[e] = v;
  }
#pragma unroll
  for (int e = 0; e < 27; e++) {
    float v = a3[e] + B3[e];
    v = fmaf(a2[e / 3], B1[e % 3], v);
    v = fmaf(a1[e / 9], B2[e % 9], v);
    a3[e] = v;
  }
#pragma unroll
  for (int e = 0; e < 9; e++) a2[e] = fmaf(a1[e / 3], B1[e % 3], a2[e] + B2[e]);
#pragma unroll
  for (int i = 0; i < 3; i++) a1[i] += B1[i];
}

// ---------------------------------------------------------------------------
// Kernel 1: signatures, reading inp directly (no transpose stage).
// inp layout: (B, C, T, V*M) -> element ((b*3+c)*300 + t)*34 + vm.
// XCD SWIZZLE (R11): p = (bid&7)*272 + (bid>>3). All 34 same-b blocks run
// on one XCD -> the 122 KB b-slice is fetched into that L2 once, reused 33x
// (verified: sig FETCH 30.7 MB -> 4.0 MB).
// Loads stay INTERLEAVED with the append loop (R12: hoisting them into a
// burst congested the VMEM path and cost ~20 us — compiler schedule wins).
// One PATH per WAVE (2176 one-wave blocks). 64 lanes x 5 Horner appends,
// then Chen combine: 4 DPP row rounds + 2 shfl_xor butterfly rounds.
// t-indices clamped to 299; invalid segments get d=0 (identity).
// 512 of the blocks zero one ht row each (b1 folded into gemm2).
// Output TRANSPOSED: St[k][b], k = vm*120 + c.
// ---------------------------------------------------------------------------
__global__ __launch_bounds__(64)
__attribute__((amdgpu_waves_per_eu(1)))
void sig_kernel(const float* __restrict__ inp, float* __restrict__ St,
                float* __restrict__ ht) {
  const int lane = threadIdx.x & 63;
  const int bid = blockIdx.x;       // 0..2175
  const int p = (bid & (NXCD - 1)) * (NPATH / NXCD) + (bid >> 3);  // bijective
  if (p < H1) ht[(size_t)p * 64 + lane] = 0.0f;  // zero-init for gemm1 atomics

  const int b = p / VM;
  const int vm = p - b * VM;
  const int t0 = lane * CHUNK;

  // base points at (b, c=0, t=0, vm); channel stride = T_PTS*VM = 10200,
  // t stride = VM = 34 (floats).
  const float* base = inp + (size_t)b * 3 * T_PTS * VM + vm;

  // Clamped point indices for this lane's 6 points.
  int tv[CHUNK + 1];
#pragma unroll
  for (int s = 0; s <= CHUNK; s++) {
    const int t = t0 + s;
    tv[s] = t < N_SEG ? t : N_SEG;
  }

  float a1[3], a2[9], a3[27], a4[81];
#pragma unroll
  for (int i = 0; i < 3; i++) a1[i] = 0.f;
#pragma unroll
  for (int i = 0; i < 9; i++) a2[i] = 0.f;
#pragma unroll
  for (int i = 0; i < 27; i++) a3[i] = 0.f;
#pragma unroll
  for (int i = 0; i < 81; i++) a4[i] = 0.f;

  float x0 = base[0 * T_PTS * VM + tv[0] * VM];
  float x1 = base[1 * T_PTS * VM + tv[0] * VM];
  float x2 = base[2 * T_PTS * VM + tv[0] * VM];
#pragma unroll
  for (int s = 0; s < CHUNK; s++) {
    const float y0 = base[0 * T_PTS * VM + tv[s + 1] * VM];
    const float y1 = base[1 * T_PTS * VM + tv[s + 1] * VM];
    const float y2 = base[2 * T_PTS * VM + tv[s + 1] * VM];
    const bool valid = (t0 + s) < N_SEG;
    const float d0 = valid ? (y0 - x0) : 0.0f;
    const float d1 = valid ? (y1 - x1) : 0.0f;
    const float d2 = valid ? (y2 - x2) : 0.0f;
    sig_append(a1, a2, a3, a4, d0, d1, d2);
    x0 = y0; x1 = y1; x2 = y2;
  }

  // Row-local suffix Chen product (16-lane Kogge-Stone via DPP).
  chen_round<1>(a1, a2, a3, a4);
  chen_round<2>(a1, a2, a3, a4);
  chen_round<4>(a1, a2, a3, a4);
  chen_round<8>(a1, a2, a3, a4);
  // Cross-row butterfly: lane 0 <- S(0..31) <- S(0..63).
  chen_round<16>(a1, a2, a3, a4);
  chen_round<32>(a1, a2, a3, a4);

  if (lane == 0) {
    float* dst = St + (size_t)(vm * SIGC) * 64 + b;  // St[(vm*120+i)*64 + b]
#pragma unroll
    for (int i = 0; i < 3; i++) dst[(size_t)i * 64] = a1[i];
#pragma unroll
    for (int i = 0; i < 9; i++) dst[(size_t)(3 + i) * 64] = a2[i];
#pragma unroll
    for (int i = 0; i < 27; i++) dst[(size_t)(12 + i) * 64] = a3[i];
#pragma unroll
    for (int i = 0; i < 81; i++) dst[(size_t)(39 + i) * 64] = a4[i];
  }
}

// ---------------------------------------------------------------------------
// Kernel 2: ht[j][b] += sum_k St[k][b] * W1[j][k].  lane = b (M=64=wave).
// 3072 waves: 48 K-splits (85 k each) x 64 j-groups (8 j each). sv[85]
// register-resident (static indices); W1 rows are wave-uniform streams
// (scalar loads). 8 independent FMA chains. Coalesced atomicAdd epilogue
// onto the zero-initialized ht (48 adds/element, order-independent).
// ---------------------------------------------------------------------------
__global__ __launch_bounds__(256) void gemm1_kernel(const float* __restrict__ St,
                                                    const float* __restrict__ W1,
                                                    float* __restrict__ ht) {
  const int lane = threadIdx.x & 63;
  int wave_id = (blockIdx.x * 256 + threadIdx.x) >> 6;        // 0..3071
  wave_id = __builtin_amdgcn_readfirstlane(wave_id);          // force SGPR
  const int ks = wave_id >> 6;    // 0..47  (k-range of 85)
  const int jg = wave_id & 63;    // 0..63  (8 j's each)
  const int k0 = ks * KW;

  const float* stp = St + (size_t)k0 * 64 + lane;
  const float* w[JPW];
#pragma unroll
  for (int r = 0; r < JPW; r++) w[r] = W1 + (size_t)(jg * JPW + r) * FAN1 + k0;  // uniform -> s_load

  float sv[KW];
#pragma unroll
  for (int i = 0; i < KW; i++) sv[i] = stp[(size_t)i * 64];

  float acc[JPW];
#pragma unroll
  for (int r = 0; r < JPW; r++) acc[r] = 0.f;

#pragma unroll
  for (int i = 0; i < KW; i++) {
#pragma unroll
    for (int r = 0; r < JPW; r++) acc[r] = fmaf(sv[i], w[r][i], acc[r]);
  }

  float* hp = ht + (size_t)(jg * JPW) * 64 + lane;
#pragma unroll
  for (int r = 0; r < JPW; r++) atomicAdd(hp + r * 64, acc[r]);
}

// ---------------------------------------------------------------------------
// Kernel 3: out[b][j] = sum_k2 (ht[k2][b] + b1[k2]) * W2[j][k2] + b2[j].
// lane = b. Block = one j; 4 waves split k2 (128 each). The b1 fold is a
// second wave-uniform FMA chain in the same loop; red[w] = acc + accb so
// the LDS reduce also sums the b1·W2[j] correction. Single non-atomic store.
// ---------------------------------------------------------------------------
__global__ __launch_bounds__(256) void gemm2_kernel(const float* __restrict__ ht,
                                                    const float* __restrict__ W2,
                                                    const float* __restrict__ b1,
                                                    const float* __restrict__ b2,
                                                    float* __restrict__ out) {
  const int j = blockIdx.x;              // 0..154
  const int lane = threadIdx.x & 63;
  int w = threadIdx.x >> 6;              // 0..3
  w = __builtin_amdgcn_readfirstlane(w);
  __shared__ float red[4][64];

  const float* htp = ht + (size_t)(w * 128) * 64 + lane;
  const float* w2r = W2 + (size_t)j * H1 + w * 128;  // uniform -> s_load
  const float* b1r = b1 + w * 128;                   // uniform -> s_load
  float acc = 0.f, accb = 0.f;
#pragma unroll 8
  for (int k = 0; k < 128; k++) {
    const float wv = w2r[k];
    acc = fmaf(wv, htp[(size_t)k * 64], acc);
    accb = fmaf(wv, b1r[k], accb);
  }

  red[w][lane] = acc + accb;
  __syncthreads();
  if (threadIdx.x < 64) {
    const float tot = red[0][lane] + red[1][lane] + red[2][lane] + red[3][lane];
    out[(size_t)lane * NOUT + j] = tot + b2[j];
  }
}

// ---------------------------------------------------------------------------
extern "C" void kernel_launch(void* const* d_in, const int* in_sizes, int n_in,
                              void* d_out, int out_size, void* d_ws, size_t ws_size,
                              hipStream_t stream) {
  const float* inp = (const float*)d_in[0];  // (64,3,300,17,2)
  const float* W1  = (const float*)d_in[1];  // (512,4080)
  const float* b1  = (const float*)d_in[2];  // (512,)
  const float* W2  = (const float*)d_in[3];  // (155,512)
  const float* b2  = (const float*)d_in[4];  // (155,)
  float* out = (float*)d_out;                // (64,155)

  // ws layout (floats): St | ht   (~1.2 MB total)
  float* St = (float*)d_ws;                  // 4080*64
  float* ht = St + (size_t)FAN1 * 64;        // 512*64

  sig_kernel<<<NPATH, 64, 0, stream>>>(inp, St, ht);
  gemm1_kernel<<<KSPL * 64 / 4, 256, 0, stream>>>(St, W1, ht);
  gemm2_kernel<<<NOUT, 256, 0, stream>>>(ht, W2, b1, b2, out);
}